// Round 10
// baseline (143.905 us; speedup 1.0000x reference)
//
#include <hip/hip_runtime.h>

// Head attention: B=32, S=2048, E=64, H=64, fp32 in/out, NO causal mask.
// R21: drop attn LDS staging entirely (guide lesson #7: staging L2-resident
// data is pure overhead -- K+V = 2MB/XCD, L2 = 4MB/XCD). K/V fragments are
// read per-lane DIRECTLY from L2 at addresses derived algebraically from the
// verified LDS path (XOR write/read cancels: slot quad^xr at row p with
// p&7==xr holds chunk quad):
//   ka00/01 = K[keyA + invperm(kh*32+lo)][quad*8..], [32+quad*8..]
//   ka10/11 = same with invperm(kh*32+16+lo)
//   vbf[ht] = Vt[h=ht*16+lo][keyA + kh*32 + quad*8..]
//   invperm(p) = (p&0x23)|((p&8)<<1)|((p&4)<<1)|((p&16)>>2)  (bijective)
// Every lane gets bit-identical values to the verified kernel -> downstream
// math unchanged. Gains: ZERO barriers in the main loop (fully async waves,
// compiler pipelines loads across iterations), -32 staging VGPRs, LDS 64KB ->
// 35KB (merge only). Each load = 16 full 64B lines, 100% utilized.
// proj: R18 config restored (grid 2048; R20's 4x amortization lost more in
// parallelism than it saved: proj+overhead 72.0 -> 76.2us).

#define BATCH 32
#define SEQ   2048
#define HS    64
#define QSCALE 0.18033688011112042f   // 0.125 * log2(e)
#define OTS   72                       // proj V-transpose row stride (halves)
#define MSTR  68                       // merge row stride (floats), 2-way banks

typedef _Float16 f16x8 __attribute__((ext_vector_type(8)));
typedef _Float16 f16x4 __attribute__((ext_vector_type(4)));
typedef float    f32x4 __attribute__((ext_vector_type(4)));
typedef unsigned int u32x4 __attribute__((ext_vector_type(4)));

__global__ __launch_bounds__(256) void proj_kernel(
    const float* __restrict__ x, const float* __restrict__ Wq,
    const float* __restrict__ Wk, const float* __restrict__ Wv,
    _Float16* __restrict__ Qh, _Float16* __restrict__ Kh,
    _Float16* __restrict__ Vt)
{
    __shared__ __align__(16) _Float16 Wl[3 * 4096];   // swizzled f16 W, 24KB
    __shared__ __align__(16) _Float16 ot[64 * OTS];   // V transpose tile, 9KB

    const int t    = threadIdx.x;
    const int w    = t >> 6;
    const int lane = t & 63;
    const int lo   = lane & 15;
    const int quad = lane >> 4;

    // ---- phase A: W f32 -> f16 into LDS, swizzled (attn K-staging algebra) --
    {
#pragma unroll
        for (int c = 0; c < 6; ++c) {
            int id  = c * 256 + t;        // 0..1535 chunks of 8 halves
            int m   = id >> 9;            // 0..2, wave-uniform (256 | 512)
            int rem = id & 511;
            int row = rem >> 3;           // 0..63 (= h)
            int q8  = rem & 7;            // chunk of 8 e-values
            const float* Ws = (m == 0) ? Wq : ((m == 1) ? Wk : Wv);
            const float* sp = Ws + row * 64 + q8 * 8;
            float4 a0 = *(const float4*)sp;
            float4 a1 = *(const float4*)(sp + 4);
            float sc = (m == 0) ? QSCALE : 1.0f;
            f16x8 h;
            h[0]=(_Float16)(a0.x*sc); h[1]=(_Float16)(a0.y*sc);
            h[2]=(_Float16)(a0.z*sc); h[3]=(_Float16)(a0.w*sc);
            h[4]=(_Float16)(a1.x*sc); h[5]=(_Float16)(a1.y*sc);
            h[6]=(_Float16)(a1.z*sc); h[7]=(_Float16)(a1.w*sc);
            *(f16x8*)(Wl + m * 4096 + row * 64 + ((q8 ^ (row & 7)) << 3)) = h;
        }
    }

    const long blk0 = (long)blockIdx.x * 64;
    const int  b    = (int)(blk0 / SEQ);
    const int  s0   = (int)(blk0 % SEQ);
    const long rw   = blk0 + w * 16;

    // x B-fragment: B[k=e][n=srow=lo]
    const float* xp = x + (rw + lo) * HS + quad * 8;
    float4 x0 = *(const float4*)xp;
    float4 x1 = *(const float4*)(xp + 4);
    float4 x2 = *(const float4*)(xp + 32);
    float4 x3 = *(const float4*)(xp + 36);
    f16x8 xb0, xb1;
    xb0[0]=(_Float16)x0.x; xb0[1]=(_Float16)x0.y; xb0[2]=(_Float16)x0.z; xb0[3]=(_Float16)x0.w;
    xb0[4]=(_Float16)x1.x; xb0[5]=(_Float16)x1.y; xb0[6]=(_Float16)x1.z; xb0[7]=(_Float16)x1.w;
    xb1[0]=(_Float16)x2.x; xb1[1]=(_Float16)x2.y; xb1[2]=(_Float16)x2.z; xb1[3]=(_Float16)x2.w;
    xb1[4]=(_Float16)x3.x; xb1[5]=(_Float16)x3.y; xb1[6]=(_Float16)x3.z; xb1[7]=(_Float16)x3.w;

    __syncthreads();   // Wl staged

#pragma unroll
    for (int m = 0; m < 3; ++m) {
        const _Float16* Wm = Wl + m * 4096;
        f32x4 acc[4];
#pragma unroll
        for (int nt = 0; nt < 4; ++nt) { acc[nt][0]=0.f; acc[nt][1]=0.f; acc[nt][2]=0.f; acc[nt][3]=0.f; }
#pragma unroll
        for (int nt = 0; nt < 4; ++nt) {
            // W A-frag from LDS: A[m=h=16nt+lo][k=e=j*8..], slot j^(row&7)
            f16x8 wa0 = *(const f16x8*)(Wm + (nt * 16 + lo) * 64 + (((quad    ) ^ (lo & 7)) << 3));
            f16x8 wa1 = *(const f16x8*)(Wm + (nt * 16 + lo) * 64 + (((4 + quad) ^ (lo & 7)) << 3));
            acc[nt] = __builtin_amdgcn_mfma_f32_16x16x32_f16(wa0, xb0, acc[nt], 0, 0, 0);
            acc[nt] = __builtin_amdgcn_mfma_f32_16x16x32_f16(wa1, xb1, acc[nt], 0, 0, 0);
        }
        // D[m=h][n=srow]: lane holds srow=lo, h=16nt+4quad+r
        if (m < 2) {
            _Float16* dst = (m == 0) ? Qh : Kh;
#pragma unroll
            for (int nt = 0; nt < 4; ++nt) {
                f16x4 pk;
                pk[0]=(_Float16)acc[nt][0]; pk[1]=(_Float16)acc[nt][1];
                pk[2]=(_Float16)acc[nt][2]; pk[3]=(_Float16)acc[nt][3];
                *(f16x4*)(dst + (rw + lo) * HS + nt * 16 + quad * 4) = pk;
            }
        } else {
            // V transposed: ot[h][srow]
#pragma unroll
            for (int nt = 0; nt < 4; ++nt)
#pragma unroll
                for (int r = 0; r < 4; ++r)
                    ot[(nt * 16 + quad * 4 + r) * OTS + w * 16 + lo] = (_Float16)acc[nt][r];
            __syncthreads();
            const int row = t >> 2, c = t & 3;
            f16x8 r0 = *(const f16x8*)(ot + row * OTS + c * 16);
            f16x8 r1 = *(const f16x8*)(ot + row * OTS + c * 16 + 8);
            _Float16* vd = Vt + ((long)b * HS + row) * SEQ + s0 + c * 16;
            *(f16x8*)vd       = r0;
            *(f16x8*)(vd + 8) = r1;
        }
    }
}

__global__ __launch_bounds__(256, 2) void attn_kernel(
    const _Float16* __restrict__ Q, const _Float16* __restrict__ K,
    const _Float16* __restrict__ Vt, float* __restrict__ out)
{
    // LDS: merge buffers only (no staging). 35328 B.
    __shared__ __align__(16) float obuf[128 * MSTR];
    __shared__ __align__(16) float lbuf[128];

    const int t    = threadIdx.x;
    const int w    = t >> 6;
    const int lane = t & 63;
    const int lo   = lane & 15;
    const int quad = lane >> 4;

    // XCD-affinity swizzle: 512 blocks; each XCD gets 4 whole batches
    const int bid = blockIdx.x;
    const int b   = (bid & 7) | ((bid >> 7) << 3);
    const int qt  = (bid >> 3) & 15;       // 16 q-blocks of 128 rows
    const int q0  = qt * 128;
    const int qh  = w >> 1;    // q half (64 rows)
    const int kh  = w & 1;     // key half (32 keys within a 64-key tile)

    // Q B-fragments for this wave's 4 q-tiles: B[k=h][n=q=lo]
    const _Float16* Qb = Q + ((long)b * SEQ + q0 + qh * 64) * HS;
    f16x8 qf[4][2];
#pragma unroll
    for (int q2 = 0; q2 < 4; ++q2) {
        qf[q2][0] = *(const f16x8*)(Qb + (q2 * 16 + lo) * HS + quad * 8);
        qf[q2][1] = *(const f16x8*)(Qb + (q2 * 16 + lo) * HS + 32 + quad * 8);
    }

    const _Float16* Kb = K  + (long)b * SEQ * HS;
    const _Float16* Vb = Vt + (long)b * HS * SEQ;

    // Per-lane permuted key indices: identical to the verified LDS row->key
    // mapping (row p held key invperm(p); the column XOR cancels to chunk
    // quad). invperm(p) = (p&0x23)|((p&8)<<1)|((p&4)<<1)|((p&16)>>2).
    const int p0  = kh * 32 + lo;
    const int p1  = kh * 32 + 16 + lo;
    const int k00 = (p0 & 0x23) | ((p0 & 8) << 1) | ((p0 & 4) << 1) | ((p0 & 16) >> 2);
    const int k10 = (p1 & 0x23) | ((p1 & 8) << 1) | ((p1 & 4) << 1) | ((p1 & 16) >> 2);

    const _Float16* kp0 = Kb + k00 * 64 + quad * 8;   // + keyA*64 (+32)
    const _Float16* kp1 = Kb + k10 * 64 + quad * 8;
    const _Float16* vp  = Vb + kh * 32 + quad * 8;    // + (ht*16+lo)*SEQ + keyA

    f32x4 o[4][4], ol[4];
#pragma unroll
    for (int q2 = 0; q2 < 4; ++q2) {
        ol[q2][0]=0.f; ol[q2][1]=0.f; ol[q2][2]=0.f; ol[q2][3]=0.f;
#pragma unroll
        for (int ht = 0; ht < 4; ++ht) { o[q2][ht][0]=0.f; o[q2][ht][1]=0.f; o[q2][ht][2]=0.f; o[q2][ht][3]=0.f; }
    }
    f32x4 zz; zz[0]=0.f; zz[1]=0.f; zz[2]=0.f; zz[3]=0.f;
    f16x8 ones;
#pragma unroll
    for (int j = 0; j < 8; ++j) ones[j] = (_Float16)1.0f;

    const int phase = (qt << 1) & 31;   // spread blocks across key tiles

#pragma unroll 2
    for (int kt = 0; kt < 32; ++kt) {
        const int keyA = ((kt + phase) & 31) << 6;

        // K A-frags direct from L2: A[m=key][k=e]
        f16x8 ka00 = *(const f16x8*)(kp0 + keyA * 64);
        f16x8 ka01 = *(const f16x8*)(kp0 + keyA * 64 + 32);
        f16x8 ka10 = *(const f16x8*)(kp1 + keyA * 64);
        f16x8 ka11 = *(const f16x8*)(kp1 + keyA * 64 + 32);

        // V B-frags direct from L2: B[k=key=kh*32+quad*8+j][n=h=ht*16+lo]
        f16x8 vbf[4];
#pragma unroll
        for (int ht = 0; ht < 4; ++ht)
            vbf[ht] = *(const f16x8*)(vp + (ht * 16 + lo) * SEQ + keyA);

#pragma unroll
        for (int q2 = 0; q2 < 4; ++q2) {
            f32x4 s0, s1;
            s0 = __builtin_amdgcn_mfma_f32_16x16x32_f16(ka00, qf[q2][0], zz, 0, 0, 0);
            s0 = __builtin_amdgcn_mfma_f32_16x16x32_f16(ka01, qf[q2][1], s0, 0, 0, 0);
            s1 = __builtin_amdgcn_mfma_f32_16x16x32_f16(ka10, qf[q2][0], zz, 0, 0, 0);
            s1 = __builtin_amdgcn_mfma_f32_16x16x32_f16(ka11, qf[q2][1], s1, 0, 0, 0);

            // fixed-scale softmax p = 2^s (raw v_exp_f32), packed via
            // v_cvt_pkrtz (RTZ; bias cancels in sumPv/sumP)
            u32x4 pw;
            pw[0] = __builtin_bit_cast(unsigned int,
                    __builtin_amdgcn_cvt_pkrtz(__builtin_amdgcn_exp2f(s0[0]),
                                               __builtin_amdgcn_exp2f(s0[1])));
            pw[1] = __builtin_bit_cast(unsigned int,
                    __builtin_amdgcn_cvt_pkrtz(__builtin_amdgcn_exp2f(s0[2]),
                                               __builtin_amdgcn_exp2f(s0[3])));
            pw[2] = __builtin_bit_cast(unsigned int,
                    __builtin_amdgcn_cvt_pkrtz(__builtin_amdgcn_exp2f(s1[0]),
                                               __builtin_amdgcn_exp2f(s1[1])));
            pw[3] = __builtin_bit_cast(unsigned int,
                    __builtin_amdgcn_cvt_pkrtz(__builtin_amdgcn_exp2f(s1[2]),
                                               __builtin_amdgcn_exp2f(s1[3])));
            f16x8 pa = __builtin_bit_cast(f16x8, pw);  // A[m=q=lo][k=quad*8+j]

            // l by MFMA: D[q][*] = sum_k P[q][k] (same f16 P as O)
            ol[q2] = __builtin_amdgcn_mfma_f32_16x16x32_f16(pa, ones, ol[q2], 0, 0, 0);
#pragma unroll
            for (int ht = 0; ht < 4; ++ht)
                o[q2][ht] = __builtin_amdgcn_mfma_f32_16x16x32_f16(pa, vbf[ht], o[q2][ht], 0, 0, 0);
        }
    }

    // ---- merge (2-way across key-half waves) ----
    // rows: q' = qh*64 + q2*16 + quad*4 + r (0..127); cols: h = ht*16 + lo
    if (kh == 0) {
#pragma unroll
        for (int q2 = 0; q2 < 4; ++q2) {
#pragma unroll
            for (int ht = 0; ht < 4; ++ht)
#pragma unroll
                for (int r = 0; r < 4; ++r)
                    obuf[(qh * 64 + q2 * 16 + quad * 4 + r) * MSTR + ht * 16 + lo] = o[q2][ht][r];
            if (lo == 0) {
#pragma unroll
                for (int r = 0; r < 4; ++r)
                    lbuf[qh * 64 + q2 * 16 + quad * 4 + r] = ol[q2][r];
            }
        }
    }
    __syncthreads();
    if (kh == 1) {
#pragma unroll
        for (int q2 = 0; q2 < 4; ++q2) {
            float linv[4];
#pragma unroll
            for (int r = 0; r < 4; ++r)
                linv[r] = 1.0f / (lbuf[qh * 64 + q2 * 16 + quad * 4 + r] + ol[q2][r]);
#pragma unroll
            for (int ht = 0; ht < 4; ++ht)
#pragma unroll
                for (int r = 0; r < 4; ++r) {
                    const int row = qh * 64 + q2 * 16 + quad * 4 + r;
                    float v = (obuf[row * MSTR + ht * 16 + lo] + o[q2][ht][r]) * linv[r];
                    out[((long)b * SEQ + q0 + row) * HS + ht * 16 + lo] = v;
                }
        }
    }
}

extern "C" void kernel_launch(void* const* d_in, const int* in_sizes, int n_in,
                              void* d_out, int out_size, void* d_ws, size_t ws_size,
                              hipStream_t stream)
{
    const float* x  = (const float*)d_in[0];
    const float* Wq = (const float*)d_in[1];
    const float* Wk = (const float*)d_in[2];
    const float* Wv = (const float*)d_in[3];
    float* out = (float*)d_out;

    const size_t E = (size_t)BATCH * SEQ * HS;   // 4,194,304
    _Float16* Qh = (_Float16*)d_ws;
    _Float16* Kh = Qh + E;
    _Float16* Vt = Kh + E;                       // ws usage: 24 MB

    proj_kernel<<<(BATCH * SEQ) / 64, 256, 0, stream>>>(x, Wq, Wk, Wv, Qh, Kh, Vt);
    attn_kernel<<<BATCH * (SEQ / 128), 256, 0, stream>>>(Qh, Kh, Vt, out);
}

// Round 11
// 135.249 us; speedup vs baseline: 1.0640x; 1.0640x over previous
//
#include <hip/hip_runtime.h>

// Head attention: B=32, S=2048, E=64, H=64, fp32 in/out, NO causal mask.
// R22: R21's direct-L2 attn regressed (45->71us: per-lane permuted-row reads
// are scattered; the staged path WAS the coalescing mechanism). Revert to the
// staged ping-pong family. New lever: occupancy without touching the proven
// schedule. R12's body (KVBLK=64 ping-pong, 32q/wave, VGPR 80, 35.8KB LDS)
// supports 4 blocks/CU by BOTH LDS and VGPR -- but ran at grid 512 = 2/CU.
// R22 = R12 attn body verbatim, 64-q blocks, grid 1024 -> 4 blocks/CU,
// 16 waves/CU. Unlike R17/R19 (changed buffering, lost overlap) this keeps
// the exact prefetch->stage->single-barrier schedule and only doubles TLP.
//  - merge: R16/R18-verified 2-way pattern halved to 64 rows.
//  - XCD affinity: b=(bid&7)|((bid>>8)<<3) -> 4 whole batches per XCD.
// proj: R18 exact (grid 2048, W->LDS swizzled, prep_w folded).
// Go/no-go: VGPR ~80-96, FETCH ~12MB (no spill), else revert R18 and stop.

#define BATCH 32
#define SEQ   2048
#define HS    64
#define QSCALE 0.18033688011112042f   // 0.125 * log2(e)
#define OTS   72                       // proj V-transpose row stride (halves)
#define MSTR  68                       // merge row stride (floats), 2-way banks

typedef _Float16 f16x8 __attribute__((ext_vector_type(8)));
typedef _Float16 f16x4 __attribute__((ext_vector_type(4)));
typedef float    f32x4 __attribute__((ext_vector_type(4)));
typedef unsigned int u32x4 __attribute__((ext_vector_type(4)));

__global__ __launch_bounds__(256) void proj_kernel(
    const float* __restrict__ x, const float* __restrict__ Wq,
    const float* __restrict__ Wk, const float* __restrict__ Wv,
    _Float16* __restrict__ Qh, _Float16* __restrict__ Kh,
    _Float16* __restrict__ Vt)
{
    __shared__ __align__(16) _Float16 Wl[3 * 4096];   // swizzled f16 W, 24KB
    __shared__ __align__(16) _Float16 ot[64 * OTS];   // V transpose tile, 9KB

    const int t    = threadIdx.x;
    const int w    = t >> 6;
    const int lane = t & 63;
    const int lo   = lane & 15;
    const int quad = lane >> 4;

    // ---- phase A: W f32 -> f16 into LDS, swizzled (attn K-staging algebra) --
    {
#pragma unroll
        for (int c = 0; c < 6; ++c) {
            int id  = c * 256 + t;        // 0..1535 chunks of 8 halves
            int m   = id >> 9;            // 0..2, wave-uniform (256 | 512)
            int rem = id & 511;
            int row = rem >> 3;           // 0..63 (= h)
            int q8  = rem & 7;            // chunk of 8 e-values
            const float* Ws = (m == 0) ? Wq : ((m == 1) ? Wk : Wv);
            const float* sp = Ws + row * 64 + q8 * 8;
            float4 a0 = *(const float4*)sp;
            float4 a1 = *(const float4*)(sp + 4);
            float sc = (m == 0) ? QSCALE : 1.0f;
            f16x8 h;
            h[0]=(_Float16)(a0.x*sc); h[1]=(_Float16)(a0.y*sc);
            h[2]=(_Float16)(a0.z*sc); h[3]=(_Float16)(a0.w*sc);
            h[4]=(_Float16)(a1.x*sc); h[5]=(_Float16)(a1.y*sc);
            h[6]=(_Float16)(a1.z*sc); h[7]=(_Float16)(a1.w*sc);
            *(f16x8*)(Wl + m * 4096 + row * 64 + ((q8 ^ (row & 7)) << 3)) = h;
        }
    }

    const long blk0 = (long)blockIdx.x * 64;
    const int  b    = (int)(blk0 / SEQ);
    const int  s0   = (int)(blk0 % SEQ);
    const long rw   = blk0 + w * 16;

    // x B-fragment: B[k=e][n=srow=lo]
    const float* xp = x + (rw + lo) * HS + quad * 8;
    float4 x0 = *(const float4*)xp;
    float4 x1 = *(const float4*)(xp + 4);
    float4 x2 = *(const float4*)(xp + 32);
    float4 x3 = *(const float4*)(xp + 36);
    f16x8 xb0, xb1;
    xb0[0]=(_Float16)x0.x; xb0[1]=(_Float16)x0.y; xb0[2]=(_Float16)x0.z; xb0[3]=(_Float16)x0.w;
    xb0[4]=(_Float16)x1.x; xb0[5]=(_Float16)x1.y; xb0[6]=(_Float16)x1.z; xb0[7]=(_Float16)x1.w;
    xb1[0]=(_Float16)x2.x; xb1[1]=(_Float16)x2.y; xb1[2]=(_Float16)x2.z; xb1[3]=(_Float16)x2.w;
    xb1[4]=(_Float16)x3.x; xb1[5]=(_Float16)x3.y; xb1[6]=(_Float16)x3.z; xb1[7]=(_Float16)x3.w;

    __syncthreads();   // Wl staged

#pragma unroll
    for (int m = 0; m < 3; ++m) {
        const _Float16* Wm = Wl + m * 4096;
        f32x4 acc[4];
#pragma unroll
        for (int nt = 0; nt < 4; ++nt) { acc[nt][0]=0.f; acc[nt][1]=0.f; acc[nt][2]=0.f; acc[nt][3]=0.f; }
#pragma unroll
        for (int nt = 0; nt < 4; ++nt) {
            // W A-frag from LDS: A[m=h=16nt+lo][k=e=j*8..], slot j^(row&7)
            f16x8 wa0 = *(const f16x8*)(Wm + (nt * 16 + lo) * 64 + (((quad    ) ^ (lo & 7)) << 3));
            f16x8 wa1 = *(const f16x8*)(Wm + (nt * 16 + lo) * 64 + (((4 + quad) ^ (lo & 7)) << 3));
            acc[nt] = __builtin_amdgcn_mfma_f32_16x16x32_f16(wa0, xb0, acc[nt], 0, 0, 0);
            acc[nt] = __builtin_amdgcn_mfma_f32_16x16x32_f16(wa1, xb1, acc[nt], 0, 0, 0);
        }
        // D[m=h][n=srow]: lane holds srow=lo, h=16nt+4quad+r
        if (m < 2) {
            _Float16* dst = (m == 0) ? Qh : Kh;
#pragma unroll
            for (int nt = 0; nt < 4; ++nt) {
                f16x4 pk;
                pk[0]=(_Float16)acc[nt][0]; pk[1]=(_Float16)acc[nt][1];
                pk[2]=(_Float16)acc[nt][2]; pk[3]=(_Float16)acc[nt][3];
                *(f16x4*)(dst + (rw + lo) * HS + nt * 16 + quad * 4) = pk;
            }
        } else {
            // V transposed: ot[h][srow]
#pragma unroll
            for (int nt = 0; nt < 4; ++nt)
#pragma unroll
                for (int r = 0; r < 4; ++r)
                    ot[(nt * 16 + quad * 4 + r) * OTS + w * 16 + lo] = (_Float16)acc[nt][r];
            __syncthreads();
            const int row = t >> 2, c = t & 3;
            f16x8 r0 = *(const f16x8*)(ot + row * OTS + c * 16);
            f16x8 r1 = *(const f16x8*)(ot + row * OTS + c * 16 + 8);
            _Float16* vd = Vt + ((long)b * HS + row) * SEQ + s0 + c * 16;
            *(f16x8*)vd       = r0;
            *(f16x8*)(vd + 8) = r1;
        }
    }
}

__global__ __launch_bounds__(256) void attn_kernel(
    const _Float16* __restrict__ Q, const _Float16* __restrict__ K,
    const _Float16* __restrict__ Vt, float* __restrict__ out)
{
    // smem union (32KB -> 4 blocks/CU):
    //  staging: ping-pong [2][8192] halves (K: first 4096, V: last 4096)
    //  merge:   obuf [64][MSTR] f32 (17408B) + lbuf [64] f32 (256B)
    __shared__ __align__(16) char smem[32768];
    _Float16* KVb  = (_Float16*)smem;
    float*    obuf = (float*)smem;
    float*    lbuf = obuf + 64 * MSTR;

    const int t    = threadIdx.x;
    const int w    = t >> 6;
    const int lane = t & 63;
    const int lo   = lane & 15;
    const int quad = lane >> 4;
    const int sr   = t >> 2, sc = t & 3;
    const int xr   = lo & 7;

    // XCD-affinity: 1024 blocks; each XCD serves 4 whole batches
    const int bid = blockIdx.x;
    const int b   = (bid & 7) | ((bid >> 8) << 3);
    const int qt  = (bid >> 3) & 31;       // 32 q-blocks of 64 rows
    const int q0  = qt * 64;
    const int qh  = w >> 1;    // q half (32 rows)
    const int kh  = w & 1;     // key half (32 keys)

    // Q B-fragments for this wave's 2 q-tiles: B[k=h][n=q=lo]
    const _Float16* Qb = Q + ((long)b * SEQ + q0 + qh * 32) * HS;
    f16x8 qf[2][2];
#pragma unroll
    for (int q2 = 0; q2 < 2; ++q2) {
        qf[q2][0] = *(const f16x8*)(Qb + (q2 * 16 + lo) * HS + quad * 8);
        qf[q2][1] = *(const f16x8*)(Qb + (q2 * 16 + lo) * HS + 32 + quad * 8);
    }

    const _Float16* Kb = K  + (long)b * SEQ * HS;
    const _Float16* Vb = Vt + (long)b * HS * SEQ;

    // K staged in permuted row order: physical key k -> LDS row
    //   (k&32) | ((k>>2)&1)*16 | ((k>>3)&3)*4 | (k&3)
    const int pr  = (sr & 32) | ((sr & 4) << 2) | ((sr & 24) >> 1) | (sr & 3);
    const int kw0 = pr * 64 + (((2 * sc    ) ^ (pr & 7)) << 3);
    const int kw1 = pr * 64 + (((2 * sc + 1) ^ (pr & 7)) << 3);
    const int vw0 = 4096 + sr * 64 + (((2 * sc    ) ^ (sr & 7)) << 3);
    const int vw1 = 4096 + sr * 64 + (((2 * sc + 1) ^ (sr & 7)) << 3);

    const int kr0 = (kh * 32      + lo) * 64;
    const int kr1 = (kh * 32 + 16 + lo) * 64;
    const int g0  = ((quad    ) ^ xr) << 3;
    const int g1  = ((4 + quad) ^ xr) << 3;
    int voff[4];
#pragma unroll
    for (int ht = 0; ht < 4; ++ht)
        voff[ht] = 4096 + (ht * 16 + lo) * 64 + (((kh * 4 + quad) ^ xr) << 3);

    f32x4 o[2][4], ol[2];
#pragma unroll
    for (int q2 = 0; q2 < 2; ++q2) {
        ol[q2][0]=0.f; ol[q2][1]=0.f; ol[q2][2]=0.f; ol[q2][3]=0.f;
#pragma unroll
        for (int ht = 0; ht < 4; ++ht) { o[q2][ht][0]=0.f; o[q2][ht][1]=0.f; o[q2][ht][2]=0.f; o[q2][ht][3]=0.f; }
    }
    f32x4 zz; zz[0]=0.f; zz[1]=0.f; zz[2]=0.f; zz[3]=0.f;
    f16x8 ones;
#pragma unroll
    for (int j = 0; j < 8; ++j) ones[j] = (_Float16)1.0f;

    // prefetch tile 0 (phase-offset start: spread blocks across key tiles)
    const int phase = qt & 31;
    const int key0  = phase << 6;
    f16x8 kfA = *(const f16x8*)(Kb + (long)(key0 + sr) * HS + sc * 16);
    f16x8 kfB = *(const f16x8*)(Kb + (long)(key0 + sr) * HS + sc * 16 + 8);
    f16x8 vfA = *(const f16x8*)(Vb + (long)sr * SEQ + key0 + sc * 16);
    f16x8 vfB = *(const f16x8*)(Vb + (long)sr * SEQ + key0 + sc * 16 + 8);

    for (int kt = 0; kt < 32; ++kt) {
        _Float16* Ksp = KVb + (kt & 1) * 8192;
        *(f16x8*)(Ksp + kw0) = kfA;
        *(f16x8*)(Ksp + kw1) = kfB;
        *(f16x8*)(Ksp + vw0) = vfA;
        *(f16x8*)(Ksp + vw1) = vfB;

        // prefetch next tile (wraps; values unused on last iter)
        const int keyn = ((kt + 1 + phase) & 31) << 6;
        kfA = *(const f16x8*)(Kb + (long)(keyn + sr) * HS + sc * 16);
        kfB = *(const f16x8*)(Kb + (long)(keyn + sr) * HS + sc * 16 + 8);
        vfA = *(const f16x8*)(Vb + (long)sr * SEQ + keyn + sc * 16);
        vfB = *(const f16x8*)(Vb + (long)sr * SEQ + keyn + sc * 16 + 8);

        __syncthreads();   // tile staged (ping-pong: single barrier/tile)

        // K A-frags: permuted rows give key = kh*32 + quad*8 + (0..3|4..7)
        f16x8 ka00 = *(const f16x8*)(Ksp + kr0 + g0);
        f16x8 ka01 = *(const f16x8*)(Ksp + kr0 + g1);
        f16x8 ka10 = *(const f16x8*)(Ksp + kr1 + g0);
        f16x8 ka11 = *(const f16x8*)(Ksp + kr1 + g1);

        // V B-frags (16x16x32): B[k=key=kh*32+quad*8+j][n=h=lo]
        f16x8 vbf[4];
#pragma unroll
        for (int ht = 0; ht < 4; ++ht)
            vbf[ht] = *(const f16x8*)(Ksp + voff[ht]);

#pragma unroll
        for (int q2 = 0; q2 < 2; ++q2) {
            f32x4 s0, s1;
            s0 = __builtin_amdgcn_mfma_f32_16x16x32_f16(ka00, qf[q2][0], zz, 0, 0, 0);
            s0 = __builtin_amdgcn_mfma_f32_16x16x32_f16(ka01, qf[q2][1], s0, 0, 0, 0);
            s1 = __builtin_amdgcn_mfma_f32_16x16x32_f16(ka10, qf[q2][0], zz, 0, 0, 0);
            s1 = __builtin_amdgcn_mfma_f32_16x16x32_f16(ka11, qf[q2][1], s1, 0, 0, 0);

            // fixed-scale softmax p = 2^s (raw v_exp_f32), packed via
            // v_cvt_pkrtz (RTZ; bias cancels in sumPv/sumP)
            u32x4 pw;
            pw[0] = __builtin_bit_cast(unsigned int,
                    __builtin_amdgcn_cvt_pkrtz(__builtin_amdgcn_exp2f(s0[0]),
                                               __builtin_amdgcn_exp2f(s0[1])));
            pw[1] = __builtin_bit_cast(unsigned int,
                    __builtin_amdgcn_cvt_pkrtz(__builtin_amdgcn_exp2f(s0[2]),
                                               __builtin_amdgcn_exp2f(s0[3])));
            pw[2] = __builtin_bit_cast(unsigned int,
                    __builtin_amdgcn_cvt_pkrtz(__builtin_amdgcn_exp2f(s1[0]),
                                               __builtin_amdgcn_exp2f(s1[1])));
            pw[3] = __builtin_bit_cast(unsigned int,
                    __builtin_amdgcn_cvt_pkrtz(__builtin_amdgcn_exp2f(s1[2]),
                                               __builtin_amdgcn_exp2f(s1[3])));
            f16x8 pa = __builtin_bit_cast(f16x8, pw);  // A[m=q=lo][k=quad*8+j]

            // l by MFMA: D[q][*] = sum_k P[q][k] (same f16 P as O)
            ol[q2] = __builtin_amdgcn_mfma_f32_16x16x32_f16(pa, ones, ol[q2], 0, 0, 0);
#pragma unroll
            for (int ht = 0; ht < 4; ++ht)
                o[q2][ht] = __builtin_amdgcn_mfma_f32_16x16x32_f16(pa, vbf[ht], o[q2][ht], 0, 0, 0);
        }
    }

    // ---- merge (2-way across key-half waves), aliasing staging LDS ----
    __syncthreads();
    // rows: q' = qh*32 + q2*16 + quad*4 + r (0..63); cols: h = ht*16 + lo
    if (kh == 0) {
#pragma unroll
        for (int q2 = 0; q2 < 2; ++q2) {
#pragma unroll
            for (int ht = 0; ht < 4; ++ht)
#pragma unroll
                for (int r = 0; r < 4; ++r)
                    obuf[(qh * 32 + q2 * 16 + quad * 4 + r) * MSTR + ht * 16 + lo] = o[q2][ht][r];
            if (lo == 0) {
#pragma unroll
                for (int r = 0; r < 4; ++r)
                    lbuf[qh * 32 + q2 * 16 + quad * 4 + r] = ol[q2][r];
            }
        }
    }
    __syncthreads();
    if (kh == 1) {
#pragma unroll
        for (int q2 = 0; q2 < 2; ++q2) {
            float linv[4];
#pragma unroll
            for (int r = 0; r < 4; ++r)
                linv[r] = 1.0f / (lbuf[qh * 32 + q2 * 16 + quad * 4 + r] + ol[q2][r]);
#pragma unroll
            for (int ht = 0; ht < 4; ++ht)
#pragma unroll
                for (int r = 0; r < 4; ++r) {
                    const int row = qh * 32 + q2 * 16 + quad * 4 + r;
                    float v = (obuf[row * MSTR + ht * 16 + lo] + o[q2][ht][r]) * linv[r];
                    out[((long)b * SEQ + q0 + row) * HS + ht * 16 + lo] = v;
                }
        }
    }
}

extern "C" void kernel_launch(void* const* d_in, const int* in_sizes, int n_in,
                              void* d_out, int out_size, void* d_ws, size_t ws_size,
                              hipStream_t stream)
{
    const float* x  = (const float*)d_in[0];
    const float* Wq = (const float*)d_in[1];
    const float* Wk = (const float*)d_in[2];
    const float* Wv = (const float*)d_in[3];
    float* out = (float*)d_out;

    const size_t E = (size_t)BATCH * SEQ * HS;   // 4,194,304
    _Float16* Qh = (_Float16*)d_ws;
    _Float16* Kh = Qh + E;
    _Float16* Vt = Kh + E;                       // ws usage: 24 MB

    proj_kernel<<<(BATCH * SEQ) / 64, 256, 0, stream>>>(x, Wq, Wk, Wv, Qh, Kh, Vt);
    attn_kernel<<<BATCH * (SEQ / 64), 256, 0, stream>>>(Qh, Kh, Vt, out);
}

// Round 12
// 117.689 us; speedup vs baseline: 1.2228x; 1.1492x over previous
//
#include <hip/hip_runtime.h>

// Head attention: B=32, S=2048, E=64, H=64, fp32 in/out, NO causal mask.
// R23 = R18 VERBATIM (measured best: 119.0us total, attn 47.0us). R22 closed
// the attn design space: lean-wave/high-occupancy (67.4us), role-wave single
// buffer (57.4), direct-L2 (70.6), DMA staging (wrong data), barrier reorder
// (67.3) ALL lose to this config -- the reuse-vs-occupancy curve peaks here:
// 64q fat waves (4 q-tiles/wave, 8 LDS reads -> 36 MFMAs), KVBLK=128
// ping-pong staged, single barrier per 128 keys, 2 blocks/CU.
// proj: prep_w folded, W f32->f16 in LDS with the attn-verified XOR swizzle.
// Residual gap to attn+proj: ~46us harness workspace re-poison (fillBuffer,
// 268MB @ 5.9TB/s) + launch overhead -- not kernel-addressable.

#define BATCH 32
#define SEQ   2048
#define HS    64
#define QSCALE 0.18033688011112042f   // 0.125 * log2(e)
#define OTS   72                       // proj V-transpose row stride (halves)
#define MSTR  68                       // merge row stride (floats), 2-way banks

typedef _Float16 f16x8 __attribute__((ext_vector_type(8)));
typedef _Float16 f16x4 __attribute__((ext_vector_type(4)));
typedef float    f32x4 __attribute__((ext_vector_type(4)));
typedef unsigned int u32x4 __attribute__((ext_vector_type(4)));

__global__ __launch_bounds__(256) void proj_kernel(
    const float* __restrict__ x, const float* __restrict__ Wq,
    const float* __restrict__ Wk, const float* __restrict__ Wv,
    _Float16* __restrict__ Qh, _Float16* __restrict__ Kh,
    _Float16* __restrict__ Vt)
{
    __shared__ __align__(16) _Float16 Wl[3 * 4096];   // swizzled f16 W, 24KB
    __shared__ __align__(16) _Float16 ot[64 * OTS];   // V transpose tile, 9KB

    const int t    = threadIdx.x;
    const int w    = t >> 6;
    const int lane = t & 63;
    const int lo   = lane & 15;
    const int quad = lane >> 4;

    // ---- phase A: W f32 -> f16 into LDS, swizzled (attn K-staging algebra) --
    {
#pragma unroll
        for (int c = 0; c < 6; ++c) {
            int id  = c * 256 + t;        // 0..1535 chunks of 8 halves
            int m   = id >> 9;            // 0..2, wave-uniform (256 | 512)
            int rem = id & 511;
            int row = rem >> 3;           // 0..63 (= h)
            int q8  = rem & 7;            // chunk of 8 e-values
            const float* Ws = (m == 0) ? Wq : ((m == 1) ? Wk : Wv);
            const float* sp = Ws + row * 64 + q8 * 8;
            float4 a0 = *(const float4*)sp;
            float4 a1 = *(const float4*)(sp + 4);
            float sc = (m == 0) ? QSCALE : 1.0f;
            f16x8 h;
            h[0]=(_Float16)(a0.x*sc); h[1]=(_Float16)(a0.y*sc);
            h[2]=(_Float16)(a0.z*sc); h[3]=(_Float16)(a0.w*sc);
            h[4]=(_Float16)(a1.x*sc); h[5]=(_Float16)(a1.y*sc);
            h[6]=(_Float16)(a1.z*sc); h[7]=(_Float16)(a1.w*sc);
            *(f16x8*)(Wl + m * 4096 + row * 64 + ((q8 ^ (row & 7)) << 3)) = h;
        }
    }

    const long blk0 = (long)blockIdx.x * 64;
    const int  b    = (int)(blk0 / SEQ);
    const int  s0   = (int)(blk0 % SEQ);
    const long rw   = blk0 + w * 16;

    // x B-fragment: B[k=e][n=srow=lo]
    const float* xp = x + (rw + lo) * HS + quad * 8;
    float4 x0 = *(const float4*)xp;
    float4 x1 = *(const float4*)(xp + 4);
    float4 x2 = *(const float4*)(xp + 32);
    float4 x3 = *(const float4*)(xp + 36);
    f16x8 xb0, xb1;
    xb0[0]=(_Float16)x0.x; xb0[1]=(_Float16)x0.y; xb0[2]=(_Float16)x0.z; xb0[3]=(_Float16)x0.w;
    xb0[4]=(_Float16)x1.x; xb0[5]=(_Float16)x1.y; xb0[6]=(_Float16)x1.z; xb0[7]=(_Float16)x1.w;
    xb1[0]=(_Float16)x2.x; xb1[1]=(_Float16)x2.y; xb1[2]=(_Float16)x2.z; xb1[3]=(_Float16)x2.w;
    xb1[4]=(_Float16)x3.x; xb1[5]=(_Float16)x3.y; xb1[6]=(_Float16)x3.z; xb1[7]=(_Float16)x3.w;

    __syncthreads();   // Wl staged

#pragma unroll
    for (int m = 0; m < 3; ++m) {
        const _Float16* Wm = Wl + m * 4096;
        f32x4 acc[4];
#pragma unroll
        for (int nt = 0; nt < 4; ++nt) { acc[nt][0]=0.f; acc[nt][1]=0.f; acc[nt][2]=0.f; acc[nt][3]=0.f; }
#pragma unroll
        for (int nt = 0; nt < 4; ++nt) {
            // W A-frag from LDS: A[m=h=16nt+lo][k=e=j*8..], slot j^(row&7)
            f16x8 wa0 = *(const f16x8*)(Wm + (nt * 16 + lo) * 64 + (((quad    ) ^ (lo & 7)) << 3));
            f16x8 wa1 = *(const f16x8*)(Wm + (nt * 16 + lo) * 64 + (((4 + quad) ^ (lo & 7)) << 3));
            acc[nt] = __builtin_amdgcn_mfma_f32_16x16x32_f16(wa0, xb0, acc[nt], 0, 0, 0);
            acc[nt] = __builtin_amdgcn_mfma_f32_16x16x32_f16(wa1, xb1, acc[nt], 0, 0, 0);
        }
        // D[m=h][n=srow]: lane holds srow=lo, h=16nt+4quad+r
        if (m < 2) {
            _Float16* dst = (m == 0) ? Qh : Kh;
#pragma unroll
            for (int nt = 0; nt < 4; ++nt) {
                f16x4 pk;
                pk[0]=(_Float16)acc[nt][0]; pk[1]=(_Float16)acc[nt][1];
                pk[2]=(_Float16)acc[nt][2]; pk[3]=(_Float16)acc[nt][3];
                *(f16x4*)(dst + (rw + lo) * HS + nt * 16 + quad * 4) = pk;
            }
        } else {
            // V transposed: ot[h][srow]
#pragma unroll
            for (int nt = 0; nt < 4; ++nt)
#pragma unroll
                for (int r = 0; r < 4; ++r)
                    ot[(nt * 16 + quad * 4 + r) * OTS + w * 16 + lo] = (_Float16)acc[nt][r];
            __syncthreads();
            const int row = t >> 2, c = t & 3;
            f16x8 r0 = *(const f16x8*)(ot + row * OTS + c * 16);
            f16x8 r1 = *(const f16x8*)(ot + row * OTS + c * 16 + 8);
            _Float16* vd = Vt + ((long)b * HS + row) * SEQ + s0 + c * 16;
            *(f16x8*)vd       = r0;
            *(f16x8*)(vd + 8) = r1;
        }
    }
}

__global__ __launch_bounds__(256, 2) void attn_kernel(
    const _Float16* __restrict__ Q, const _Float16* __restrict__ K,
    const _Float16* __restrict__ Vt, float* __restrict__ out)
{
    // smem union:
    //  staging: 2 buffers x 16384 halves; each buffer = 2 sub-tiles of
    //           [K: 4096 | V: 4096] halves (R12 sub-tile layout, x2). 64KB.
    //  merge:   obuf [128][MSTR] f32 (34816B) + lbuf [128] f32 (512B)
    __shared__ __align__(16) char smem[65536];
    _Float16* KVb  = (_Float16*)smem;
    float*    obuf = (float*)smem;
    float*    lbuf = obuf + 128 * MSTR;

    const int t    = threadIdx.x;
    const int w    = t >> 6;
    const int lane = t & 63;
    const int lo   = lane & 15;
    const int quad = lane >> 4;
    const int sr   = t >> 2, sc = t & 3;
    const int xr   = lo & 7;

    // XCD-affinity swizzle: 512 blocks; each XCD gets 4 whole batches
    const int bid = blockIdx.x;
    const int b   = (bid & 7) | ((bid >> 7) << 3);
    const int qt  = (bid >> 3) & 15;       // 16 q-blocks of 128 rows
    const int q0  = qt * 128;
    const int qh  = w >> 1;    // q half (64 rows)
    const int kh  = w & 1;     // key half (32 keys within a 64-key sub-tile)

    // Q B-fragments for this wave's 4 q-tiles: B[k=h][n=q=lo]
    const _Float16* Qb = Q + ((long)b * SEQ + q0 + qh * 64) * HS;
    f16x8 qf[4][2];
#pragma unroll
    for (int q2 = 0; q2 < 4; ++q2) {
        qf[q2][0] = *(const f16x8*)(Qb + (q2 * 16 + lo) * HS + quad * 8);
        qf[q2][1] = *(const f16x8*)(Qb + (q2 * 16 + lo) * HS + 32 + quad * 8);
    }

    const _Float16* Kb = K  + (long)b * SEQ * HS;
    const _Float16* Vb = Vt + (long)b * HS * SEQ;

    // K staged in permuted row order: physical key k -> LDS row
    //   (k&32) | ((k>>2)&1)*16 | ((k>>3)&3)*4 | (k&3)     (per 64-key sub-tile)
    const int pr  = (sr & 32) | ((sr & 4) << 2) | ((sr & 24) >> 1) | (sr & 3);
    const int kw0 = pr * 64 + (((2 * sc    ) ^ (pr & 7)) << 3);
    const int kw1 = pr * 64 + (((2 * sc + 1) ^ (pr & 7)) << 3);
    const int vw0 = 4096 + sr * 64 + (((2 * sc    ) ^ (sr & 7)) << 3);
    const int vw1 = 4096 + sr * 64 + (((2 * sc + 1) ^ (sr & 7)) << 3);

    const int kr0 = (kh * 32      + lo) * 64;
    const int kr1 = (kh * 32 + 16 + lo) * 64;
    const int g0  = ((quad    ) ^ xr) << 3;
    const int g1  = ((4 + quad) ^ xr) << 3;
    int voff[4];
#pragma unroll
    for (int ht = 0; ht < 4; ++ht)
        voff[ht] = 4096 + (ht * 16 + lo) * 64 + (((kh * 4 + quad) ^ xr) << 3);

    f32x4 o[4][4], ol[4];
#pragma unroll
    for (int q2 = 0; q2 < 4; ++q2) {
        ol[q2][0]=0.f; ol[q2][1]=0.f; ol[q2][2]=0.f; ol[q2][3]=0.f;
#pragma unroll
        for (int ht = 0; ht < 4; ++ht) { o[q2][ht][0]=0.f; o[q2][ht][1]=0.f; o[q2][ht][2]=0.f; o[q2][ht][3]=0.f; }
    }
    f32x4 zz; zz[0]=0.f; zz[1]=0.f; zz[2]=0.f; zz[3]=0.f;
    f16x8 ones;
#pragma unroll
    for (int j = 0; j < 8; ++j) ones[j] = (_Float16)1.0f;

    // prefetch tile-pair 0 (phase-offset start; phase even so the pair
    // (2*kt2+phase, 2*kt2+1+phase) never wraps mid-pair)
    const int phase = qt << 1;
    const int key0 = (phase & 31) << 6;
    f16x8 kfA0 = *(const f16x8*)(Kb + (long)(key0 + sr) * HS + sc * 16);
    f16x8 kfB0 = *(const f16x8*)(Kb + (long)(key0 + sr) * HS + sc * 16 + 8);
    f16x8 vfA0 = *(const f16x8*)(Vb + (long)sr * SEQ + key0 + sc * 16);
    f16x8 vfB0 = *(const f16x8*)(Vb + (long)sr * SEQ + key0 + sc * 16 + 8);
    f16x8 kfA1 = *(const f16x8*)(Kb + (long)(key0 + 64 + sr) * HS + sc * 16);
    f16x8 kfB1 = *(const f16x8*)(Kb + (long)(key0 + 64 + sr) * HS + sc * 16 + 8);
    f16x8 vfA1 = *(const f16x8*)(Vb + (long)sr * SEQ + key0 + 64 + sc * 16);
    f16x8 vfB1 = *(const f16x8*)(Vb + (long)sr * SEQ + key0 + 64 + sc * 16 + 8);

    for (int kt2 = 0; kt2 < 16; ++kt2) {
        _Float16* Bp = KVb + (kt2 & 1) * 16384;
        *(f16x8*)(Bp + kw0) = kfA0;
        *(f16x8*)(Bp + kw1) = kfB0;
        *(f16x8*)(Bp + vw0) = vfA0;
        *(f16x8*)(Bp + vw1) = vfB0;
        *(f16x8*)(Bp + 8192 + kw0) = kfA1;
        *(f16x8*)(Bp + 8192 + kw1) = kfB1;
        *(f16x8*)(Bp + 8192 + vw0) = vfA1;
        *(f16x8*)(Bp + 8192 + vw1) = vfB1;

        // prefetch next pair (wraps; values unused on last iter)
        const int keyn = ((2 * kt2 + 2 + phase) & 31) << 6;
        kfA0 = *(const f16x8*)(Kb + (long)(keyn + sr) * HS + sc * 16);
        kfB0 = *(const f16x8*)(Kb + (long)(keyn + sr) * HS + sc * 16 + 8);
        vfA0 = *(const f16x8*)(Vb + (long)sr * SEQ + keyn + sc * 16);
        vfB0 = *(const f16x8*)(Vb + (long)sr * SEQ + keyn + sc * 16 + 8);
        kfA1 = *(const f16x8*)(Kb + (long)(keyn + 64 + sr) * HS + sc * 16);
        kfB1 = *(const f16x8*)(Kb + (long)(keyn + 64 + sr) * HS + sc * 16 + 8);
        vfA1 = *(const f16x8*)(Vb + (long)sr * SEQ + keyn + 64 + sc * 16);
        vfB1 = *(const f16x8*)(Vb + (long)sr * SEQ + keyn + 64 + sc * 16 + 8);

        __syncthreads();   // pair staged (ping-pong: single barrier/128 keys)

#pragma unroll
        for (int sub = 0; sub < 2; ++sub) {
            _Float16* Ksp = Bp + sub * 8192;

            // K A-frags: permuted rows give key = kh*32 + quad*8 + (0..3|4..7)
            f16x8 ka00 = *(const f16x8*)(Ksp + kr0 + g0);
            f16x8 ka01 = *(const f16x8*)(Ksp + kr0 + g1);
            f16x8 ka10 = *(const f16x8*)(Ksp + kr1 + g0);
            f16x8 ka11 = *(const f16x8*)(Ksp + kr1 + g1);

            // V B-frags (16x16x32): B[k=key=kh*32+quad*8+j][n=h=lo]
            f16x8 vbf[4];
#pragma unroll
            for (int ht = 0; ht < 4; ++ht)
                vbf[ht] = *(const f16x8*)(Ksp + voff[ht]);

#pragma unroll
            for (int q2 = 0; q2 < 4; ++q2) {
                f32x4 s0, s1;
                s0 = __builtin_amdgcn_mfma_f32_16x16x32_f16(ka00, qf[q2][0], zz, 0, 0, 0);
                s0 = __builtin_amdgcn_mfma_f32_16x16x32_f16(ka01, qf[q2][1], s0, 0, 0, 0);
                s1 = __builtin_amdgcn_mfma_f32_16x16x32_f16(ka10, qf[q2][0], zz, 0, 0, 0);
                s1 = __builtin_amdgcn_mfma_f32_16x16x32_f16(ka11, qf[q2][1], s1, 0, 0, 0);

                // fixed-scale softmax p = 2^s (raw v_exp_f32), packed via
                // v_cvt_pkrtz (RTZ; bias cancels in sumPv/sumP)
                u32x4 pw;
                pw[0] = __builtin_bit_cast(unsigned int,
                        __builtin_amdgcn_cvt_pkrtz(__builtin_amdgcn_exp2f(s0[0]),
                                                   __builtin_amdgcn_exp2f(s0[1])));
                pw[1] = __builtin_bit_cast(unsigned int,
                        __builtin_amdgcn_cvt_pkrtz(__builtin_amdgcn_exp2f(s0[2]),
                                                   __builtin_amdgcn_exp2f(s0[3])));
                pw[2] = __builtin_bit_cast(unsigned int,
                        __builtin_amdgcn_cvt_pkrtz(__builtin_amdgcn_exp2f(s1[0]),
                                                   __builtin_amdgcn_exp2f(s1[1])));
                pw[3] = __builtin_bit_cast(unsigned int,
                        __builtin_amdgcn_cvt_pkrtz(__builtin_amdgcn_exp2f(s1[2]),
                                                   __builtin_amdgcn_exp2f(s1[3])));
                f16x8 pa = __builtin_bit_cast(f16x8, pw);  // A[m=q=lo][k=quad*8+j]

                // l by MFMA: D[q][*] = sum_k P[q][k] (same f16 P as O)
                ol[q2] = __builtin_amdgcn_mfma_f32_16x16x32_f16(pa, ones, ol[q2], 0, 0, 0);
#pragma unroll
                for (int ht = 0; ht < 4; ++ht)
                    o[q2][ht] = __builtin_amdgcn_mfma_f32_16x16x32_f16(pa, vbf[ht], o[q2][ht], 0, 0, 0);
            }
        }
    }

    // ---- merge (2-way across key-half waves), aliasing staging LDS ----
    __syncthreads();
    // rows: q' = qh*64 + q2*16 + quad*4 + r (0..127); cols: h = ht*16 + lo
    if (kh == 0) {
#pragma unroll
        for (int q2 = 0; q2 < 4; ++q2) {
#pragma unroll
            for (int ht = 0; ht < 4; ++ht)
#pragma unroll
                for (int r = 0; r < 4; ++r)
                    obuf[(qh * 64 + q2 * 16 + quad * 4 + r) * MSTR + ht * 16 + lo] = o[q2][ht][r];
            if (lo == 0) {
#pragma unroll
                for (int r = 0; r < 4; ++r)
                    lbuf[qh * 64 + q2 * 16 + quad * 4 + r] = ol[q2][r];
            }
        }
    }
    __syncthreads();
    if (kh == 1) {
#pragma unroll
        for (int q2 = 0; q2 < 4; ++q2) {
            float linv[4];
#pragma unroll
            for (int r = 0; r < 4; ++r)
                linv[r] = 1.0f / (lbuf[qh * 64 + q2 * 16 + quad * 4 + r] + ol[q2][r]);
#pragma unroll
            for (int ht = 0; ht < 4; ++ht)
#pragma unroll
                for (int r = 0; r < 4; ++r) {
                    const int row = qh * 64 + q2 * 16 + quad * 4 + r;
                    float v = (obuf[row * MSTR + ht * 16 + lo] + o[q2][ht][r]) * linv[r];
                    out[((long)b * SEQ + q0 + row) * HS + ht * 16 + lo] = v;
                }
        }
    }
}

extern "C" void kernel_launch(void* const* d_in, const int* in_sizes, int n_in,
                              void* d_out, int out_size, void* d_ws, size_t ws_size,
                              hipStream_t stream)
{
    const float* x  = (const float*)d_in[0];
    const float* Wq = (const float*)d_in[1];
    const float* Wk = (const float*)d_in[2];
    const float* Wv = (const float*)d_in[3];
    float* out = (float*)d_out;

    const size_t E = (size_t)BATCH * SEQ * HS;   // 4,194,304
    _Float16* Qh = (_Float16*)d_ws;
    _Float16* Kh = Qh + E;
    _Float16* Vt = Kh + E;                       // ws usage: 24 MB

    proj_kernel<<<(BATCH * SEQ) / 64, 256, 0, stream>>>(x, Wq, Wk, Wv, Qh, Kh, Vt);
    attn_kernel<<<BATCH * (SEQ / 128), 256, 0, stream>>>(Qh, Kh, Vt, out);
}